// Round 11
// baseline (479.846 us; speedup 1.0000x reference)
//
#include <hip/hip_runtime.h>

// GRU: H=32, I=1, B=2048, T=1024, fused output Linear(32,1).
// v11: dual-stream software pipeline. v10's wall = 638 cyc/step = one full
// serial chain (LDS publish->broadcast RT ~350 + dot2 96 + tail ~70) with
// nothing to hide it (1 wave/SIMD). Now each wave carries TWO independent
// batch-pairs (streams P,Q): while P's 7-op DS group (y,pub,4xb128,x) is in
// flight, the wave computes Q's dot2+tail, and vice versa, synchronized by
// s_waitcnt lgkmcnt(7) (waits only the OLDER stream's group; DS completes
// in order). Weights are shared between streams (same lane->row mapping).
// 512 waves x 4 batches; prologue mirrors steady state (dummy y-write) so
// the lgkmcnt arithmetic is uniform. y-stash stride 36 -> 33 (kills v10's
// 5.7M bank-conflict cycles). TRANS wait states kept exactly as v10.

constexpr int H  = 32;
constexpr int TT = 1024;
constexpr int BB = 2048;

typedef _Float16 hf2 __attribute__((ext_vector_type(2)));

__device__ __forceinline__ unsigned pack2(float a, float b) {
    hf2 t; t.x = (_Float16)a; t.y = (_Float16)b;
    return __builtin_bit_cast(unsigned, t);
}

#define DOT2_SET(QA, QB, QC, QD)                                   \
    "v_dot2_f32_f16 v68, %[r0], " QA ", %[br]\n\t"                 \
    "v_dot2_f32_f16 v69, %[z0], " QA ", %[bz]\n\t"                 \
    "v_dot2_f32_f16 v70, %[n0], " QA ", %[bn]\n\t"                 \
    "v_dot2_f32_f16 v68, %[r1], " QA "1, v68\n\t"

__global__ __launch_bounds__(128, 1)
void gru_fused(const float* __restrict__ x,      // [B,T]
               const float* __restrict__ h0,     // [1,B,H]
               const float* __restrict__ W_ih,   // [3H,1]
               const float* __restrict__ W_hh,   // [3H,H]
               const float* __restrict__ b_ih,   // [3H]
               const float* __restrict__ b_hh,   // [3H]
               const float* __restrict__ W_out,  // [1,H]
               const float* __restrict__ b_out,  // [1]
               float* __restrict__ out)          // y[B,T] ++ h_n[B,H]
{
    __shared__ __align__(16) _Float16 hbuf[2][2][64];   // [wave][stream][half*32+j]
    __shared__ float xst[2][2][2][34];                  // [wave][stream][half][step]
    __shared__ float ybuf[2][2][2][33 * 32];            // [wave][stream][half][33*s+j]

    const int tid  = threadIdx.x;
    const int w    = tid >> 6;          // 0..1
    const int lane = tid & 63;
    const int half = lane >> 5;
    const int j    = lane & 31;
    const int g    = (blockIdx.x << 1) | w;   // 0..511
    const int bP   = (g << 2) | half;         // stream P batch
    const int bQ   = bP + 2;                  // stream Q batch

    const float NL2E = -1.44269504f;
    const float P2L2 =  2.88539008f;

    // weights: FULL rows {j, H+j, 2H+j}, f16 pairs, shared by both streams
    const float* Wrp = &W_hh[(0 * H + j) * H];
    const float* Wzp = &W_hh[(1 * H + j) * H];
    const float* Wnp = &W_hh[(2 * H + j) * H];
    unsigned wr[16], wz[16], wn[16];
#pragma unroll
    for (int k = 0; k < 16; ++k) {
        wr[k] = pack2(Wrp[2 * k] * NL2E, Wrp[2 * k + 1] * NL2E);
        wz[k] = pack2(Wzp[2 * k] * NL2E, Wzp[2 * k + 1] * NL2E);
        wn[k] = pack2(Wnp[2 * k] * P2L2, Wnp[2 * k + 1] * P2L2);
    }
    const float wir = W_ih[j] * NL2E;
    const float wiz = W_ih[H + j] * NL2E;
    const float br  = (b_ih[j] + b_hh[j]) * NL2E;
    const float bz  = (b_ih[H + j] + b_hh[H + j]) * NL2E;
    const float bhn = b_hh[2 * H + j] * P2L2;
    const float win = W_ih[2 * H + j] * P2L2;
    const float bin = b_ih[2 * H + j] * P2L2;
    const float wo  = W_out[j];
    const float bo  = b_out[0];

    float hP = h0[bP * H + j];
    float hQ = h0[bQ * H + j];

    const float* xbP = x + (size_t)bP * TT;
    const float* xbQ = x + (size_t)bQ * TT;
    float*       ybP = out + (size_t)bP * TT;
    float*       ybQ = out + (size_t)bQ * TT;

    // LDS addresses (P at offset 0; Q via fixed immediate offsets)
    const unsigned ha = (unsigned)(size_t)&hbuf[w][0][half * 32 + j]; // +128 for Q
    const unsigned hr = (unsigned)(size_t)&hbuf[w][0][half * 32];     // +128 for Q
    const unsigned xw = (unsigned)(size_t)&xst[w][0][half][j];        // +272 for Q
    const unsigned xa = (unsigned)(size_t)&xst[w][0][half][0];        // +272 for Q
    const unsigned ya = (unsigned)(size_t)&ybuf[w][0][half][j];       // +8448 for Q
    const float* yrP = &ybuf[w][0][half][0];
    const float* yrQ = &ybuf[w][1][half][0];

#pragma unroll 1
    for (int t0 = 0; t0 < TT; t0 += 32) {
        const float xvP = xbP[t0 + j];
        const float xvQ = xbQ[t0 + j];

        asm volatile(
            "s_mov_b32 s20, 32\n\t"
            "v_mov_b32 v82, %[ya]\n\t"
            "v_mov_b32 v83, %[xa]\n\t"
            // prologue: stage x, then mirror steady-state 7-op groups
            "ds_write_b32 %[xw], %[xvP]\n\t"
            "ds_write_b32 %[xw], %[xvQ] offset:272\n\t"
            // Q group (dummy-y, pub, 4 reads, x)
            "ds_write_b32 v82, v78 offset:8448\n\t"
            "v_cvt_f16_f32 v33, %[hQ]\n\t"
            "ds_write_b16 %[ha], v33 offset:128\n\t"
            "ds_read_b128 v[36:39], %[hr] offset:128\n\t"
            "ds_read_b128 v[40:43], %[hr] offset:144\n\t"
            "ds_read_b128 v[44:47], %[hr] offset:160\n\t"
            "ds_read_b128 v[48:51], %[hr] offset:176\n\t"
            "ds_read_b32 v80, v83 offset:272\n\t"
            // P group
            "ds_write_b32 v82, v78\n\t"
            "v_cvt_f16_f32 v33, %[hP]\n\t"
            "ds_write_b16 %[ha], v33\n\t"
            "ds_read_b128 v[52:55], %[hr]\n\t"
            "ds_read_b128 v[56:59], %[hr] offset:16\n\t"
            "ds_read_b128 v[60:63], %[hr] offset:32\n\t"
            "ds_read_b128 v[64:67], %[hr] offset:48\n\t"
            "ds_read_b32 v81, v83\n\t"

            "L_gru_%=:\n\t"
            // ================= phase Q =================
            "s_waitcnt lgkmcnt(7)\n\t"          // Q's group landed
            "v_dot2_f32_f16 v68, %[r0], v36, %[br]\n\t"
            "v_dot2_f32_f16 v69, %[z0], v36, %[bz]\n\t"
            "v_dot2_f32_f16 v70, %[n0], v36, %[bn]\n\t"
            "v_dot2_f32_f16 v68, %[r1], v37, v68\n\t"
            "v_dot2_f32_f16 v69, %[z1], v37, v69\n\t"
            "v_dot2_f32_f16 v70, %[n1], v37, v70\n\t"
            "v_dot2_f32_f16 v68, %[r2], v38, v68\n\t"
            "v_dot2_f32_f16 v69, %[z2], v38, v69\n\t"
            "v_dot2_f32_f16 v70, %[n2], v38, v70\n\t"
            "v_dot2_f32_f16 v68, %[r3], v39, v68\n\t"
            "v_dot2_f32_f16 v69, %[z3], v39, v69\n\t"
            "v_dot2_f32_f16 v70, %[n3], v39, v70\n\t"
            "v_dot2_f32_f16 v68, %[r4], v40, v68\n\t"
            "v_dot2_f32_f16 v69, %[z4], v40, v69\n\t"
            "v_dot2_f32_f16 v70, %[n4], v40, v70\n\t"
            "v_dot2_f32_f16 v68, %[r5], v41, v68\n\t"
            "v_dot2_f32_f16 v69, %[z5], v41, v69\n\t"
            "v_dot2_f32_f16 v70, %[n5], v41, v70\n\t"
            "v_dot2_f32_f16 v68, %[r6], v42, v68\n\t"
            "v_dot2_f32_f16 v69, %[z6], v42, v69\n\t"
            "v_dot2_f32_f16 v70, %[n6], v42, v70\n\t"
            "v_dot2_f32_f16 v68, %[r7], v43, v68\n\t"
            "v_dot2_f32_f16 v69, %[z7], v43, v69\n\t"
            "v_dot2_f32_f16 v70, %[n7], v43, v70\n\t"
            "v_dot2_f32_f16 v68, %[r8], v44, v68\n\t"
            "v_dot2_f32_f16 v69, %[z8], v44, v69\n\t"
            "v_dot2_f32_f16 v70, %[n8], v44, v70\n\t"
            "v_dot2_f32_f16 v68, %[r9], v45, v68\n\t"
            "v_dot2_f32_f16 v69, %[z9], v45, v69\n\t"
            "v_dot2_f32_f16 v70, %[n9], v45, v70\n\t"
            "v_dot2_f32_f16 v68, %[r10], v46, v68\n\t"
            "v_dot2_f32_f16 v69, %[z10], v46, v69\n\t"
            "v_dot2_f32_f16 v70, %[n10], v46, v70\n\t"
            "v_dot2_f32_f16 v68, %[r11], v47, v68\n\t"
            "v_dot2_f32_f16 v69, %[z11], v47, v69\n\t"
            "v_dot2_f32_f16 v70, %[n11], v47, v70\n\t"
            "v_dot2_f32_f16 v68, %[r12], v48, v68\n\t"
            "v_dot2_f32_f16 v69, %[z12], v48, v69\n\t"
            "v_dot2_f32_f16 v70, %[n12], v48, v70\n\t"
            "v_dot2_f32_f16 v68, %[r13], v49, v68\n\t"
            "v_dot2_f32_f16 v69, %[z13], v49, v69\n\t"
            "v_dot2_f32_f16 v70, %[n13], v49, v70\n\t"
            "v_dot2_f32_f16 v68, %[r14], v50, v68\n\t"
            "v_dot2_f32_f16 v69, %[z14], v50, v69\n\t"
            "v_dot2_f32_f16 v70, %[n14], v50, v70\n\t"
            "v_dot2_f32_f16 v68, %[r15], v51, v68\n\t"
            "v_dot2_f32_f16 v69, %[z15], v51, v69\n\t"
            "v_dot2_f32_f16 v70, %[n15], v51, v70\n\t"
            "v_fmac_f32 v68, v80, %[wir]\n\t"
            "v_fmac_f32 v69, v80, %[wiz]\n\t"
            "v_exp_f32 v71, v68\n\t"
            "v_exp_f32 v72, v69\n\t"
            "v_fma_f32 v74, v80, %[wi], %[bi]\n\t"
            "s_nop 2\n\t"
            "v_add_f32 v71, 1.0, v71\n\t"
            "v_add_f32 v72, 1.0, v72\n\t"
            "v_rcp_f32 v71, v71\n\t"
            "v_rcp_f32 v72, v72\n\t"
            "s_nop 2\n\t"
            "v_fmac_f32 v74, v71, v70\n\t"
            "v_exp_f32 v75, v74\n\t"
            "s_nop 2\n\t"
            "v_add_f32 v75, 1.0, v75\n\t"
            "v_rcp_f32 v75, v75\n\t"
            "s_nop 2\n\t"
            "v_fma_f32 v76, -2.0, v75, 1.0\n\t"
            "v_sub_f32 v77, %[hQ], v76\n\t"
            "v_fma_f32 %[hQ], v72, v77, v76\n\t"
            "v_mul_f32 v78, %[wo], %[hQ]\n\t"
            "ds_write_b32 v82, v78 offset:8448\n\t"
            "v_cvt_f16_f32 v33, %[hQ]\n\t"
            "ds_write_b16 %[ha], v33 offset:128\n\t"
            "ds_read_b128 v[36:39], %[hr] offset:128\n\t"
            "ds_read_b128 v[40:43], %[hr] offset:144\n\t"
            "ds_read_b128 v[44:47], %[hr] offset:160\n\t"
            "ds_read_b128 v[48:51], %[hr] offset:176\n\t"
            "ds_read_b32 v80, v83 offset:276\n\t"
            // ================= phase P =================
            "s_waitcnt lgkmcnt(7)\n\t"          // P's group landed
            "v_dot2_f32_f16 v68, %[r0], v52, %[br]\n\t"
            "v_dot2_f32_f16 v69, %[z0], v52, %[bz]\n\t"
            "v_dot2_f32_f16 v70, %[n0], v52, %[bn]\n\t"
            "v_dot2_f32_f16 v68, %[r1], v53, v68\n\t"
            "v_dot2_f32_f16 v69, %[z1], v53, v69\n\t"
            "v_dot2_f32_f16 v70, %[n1], v53, v70\n\t"
            "v_dot2_f32_f16 v68, %[r2], v54, v68\n\t"
            "v_dot2_f32_f16 v69, %[z2], v54, v69\n\t"
            "v_dot2_f32_f16 v70, %[n2], v54, v70\n\t"
            "v_dot2_f32_f16 v68, %[r3], v55, v68\n\t"
            "v_dot2_f32_f16 v69, %[z3], v55, v69\n\t"
            "v_dot2_f32_f16 v70, %[n3], v55, v70\n\t"
            "v_dot2_f32_f16 v68, %[r4], v56, v68\n\t"
            "v_dot2_f32_f16 v69, %[z4], v56, v69\n\t"
            "v_dot2_f32_f16 v70, %[n4], v56, v70\n\t"
            "v_dot2_f32_f16 v68, %[r5], v57, v68\n\t"
            "v_dot2_f32_f16 v69, %[z5], v57, v69\n\t"
            "v_dot2_f32_f16 v70, %[n5], v57, v70\n\t"
            "v_dot2_f32_f16 v68, %[r6], v58, v68\n\t"
            "v_dot2_f32_f16 v69, %[z6], v58, v69\n\t"
            "v_dot2_f32_f16 v70, %[n6], v58, v70\n\t"
            "v_dot2_f32_f16 v68, %[r7], v59, v68\n\t"
            "v_dot2_f32_f16 v69, %[z7], v59, v69\n\t"
            "v_dot2_f32_f16 v70, %[n7], v59, v70\n\t"
            "v_dot2_f32_f16 v68, %[r8], v60, v68\n\t"
            "v_dot2_f32_f16 v69, %[z8], v60, v69\n\t"
            "v_dot2_f32_f16 v70, %[n8], v60, v70\n\t"
            "v_dot2_f32_f16 v68, %[r9], v61, v68\n\t"
            "v_dot2_f32_f16 v69, %[z9], v61, v69\n\t"
            "v_dot2_f32_f16 v70, %[n9], v61, v70\n\t"
            "v_dot2_f32_f16 v68, %[r10], v62, v68\n\t"
            "v_dot2_f32_f16 v69, %[z10], v62, v69\n\t"
            "v_dot2_f32_f16 v70, %[n10], v62, v70\n\t"
            "v_dot2_f32_f16 v68, %[r11], v63, v68\n\t"
            "v_dot2_f32_f16 v69, %[z11], v63, v69\n\t"
            "v_dot2_f32_f16 v70, %[n11], v63, v70\n\t"
            "v_dot2_f32_f16 v68, %[r12], v64, v68\n\t"
            "v_dot2_f32_f16 v69, %[z12], v64, v69\n\t"
            "v_dot2_f32_f16 v70, %[n12], v64, v70\n\t"
            "v_dot2_f32_f16 v68, %[r13], v65, v68\n\t"
            "v_dot2_f32_f16 v69, %[z13], v65, v69\n\t"
            "v_dot2_f32_f16 v70, %[n13], v65, v70\n\t"
            "v_dot2_f32_f16 v68, %[r14], v66, v68\n\t"
            "v_dot2_f32_f16 v69, %[z14], v66, v69\n\t"
            "v_dot2_f32_f16 v70, %[n14], v66, v70\n\t"
            "v_dot2_f32_f16 v68, %[r15], v67, v68\n\t"
            "v_dot2_f32_f16 v69, %[z15], v67, v69\n\t"
            "v_dot2_f32_f16 v70, %[n15], v67, v70\n\t"
            "v_fmac_f32 v68, v81, %[wir]\n\t"
            "v_fmac_f32 v69, v81, %[wiz]\n\t"
            "v_exp_f32 v71, v68\n\t"
            "v_exp_f32 v72, v69\n\t"
            "v_fma_f32 v74, v81, %[wi], %[bi]\n\t"
            "s_nop 2\n\t"
            "v_add_f32 v71, 1.0, v71\n\t"
            "v_add_f32 v72, 1.0, v72\n\t"
            "v_rcp_f32 v71, v71\n\t"
            "v_rcp_f32 v72, v72\n\t"
            "s_nop 2\n\t"
            "v_fmac_f32 v74, v71, v70\n\t"
            "v_exp_f32 v75, v74\n\t"
            "s_nop 2\n\t"
            "v_add_f32 v75, 1.0, v75\n\t"
            "v_rcp_f32 v75, v75\n\t"
            "s_nop 2\n\t"
            "v_fma_f32 v76, -2.0, v75, 1.0\n\t"
            "v_sub_f32 v77, %[hP], v76\n\t"
            "v_fma_f32 %[hP], v72, v77, v76\n\t"
            "v_mul_f32 v78, %[wo], %[hP]\n\t"
            "ds_write_b32 v82, v78\n\t"
            "v_cvt_f16_f32 v33, %[hP]\n\t"
            "ds_write_b16 %[ha], v33\n\t"
            "ds_read_b128 v[52:55], %[hr]\n\t"
            "ds_read_b128 v[56:59], %[hr] offset:16\n\t"
            "ds_read_b128 v[60:63], %[hr] offset:32\n\t"
            "ds_read_b128 v[64:67], %[hr] offset:48\n\t"
            "ds_read_b32 v81, v83 offset:4\n\t"
            // bookkeeping
            "v_add_u32 v82, 132, v82\n\t"
            "v_add_u32 v83, 4, v83\n\t"
            "s_sub_i32 s20, s20, 1\n\t"
            "s_cmp_gt_i32 s20, 0\n\t"
            "s_cbranch_scc1 L_gru_%=\n\t"
            "s_waitcnt lgkmcnt(0)"
            : [hP]"+v"(hP), [hQ]"+v"(hQ)
            : [xvP]"v"(xvP), [xvQ]"v"(xvQ),
              [ha]"v"(ha), [hr]"v"(hr), [xw]"v"(xw), [xa]"v"(xa), [ya]"v"(ya),
              [wir]"v"(wir), [wiz]"v"(wiz), [wi]"v"(win), [bi]"v"(bin),
              [wo]"v"(wo), [br]"v"(br), [bz]"v"(bz), [bn]"v"(bhn),
              [r0]"v"(wr[0]), [r1]"v"(wr[1]), [r2]"v"(wr[2]), [r3]"v"(wr[3]),
              [r4]"v"(wr[4]), [r5]"v"(wr[5]), [r6]"v"(wr[6]), [r7]"v"(wr[7]),
              [r8]"v"(wr[8]), [r9]"v"(wr[9]), [r10]"v"(wr[10]), [r11]"v"(wr[11]),
              [r12]"v"(wr[12]), [r13]"v"(wr[13]), [r14]"v"(wr[14]), [r15]"v"(wr[15]),
              [z0]"v"(wz[0]), [z1]"v"(wz[1]), [z2]"v"(wz[2]), [z3]"v"(wz[3]),
              [z4]"v"(wz[4]), [z5]"v"(wz[5]), [z6]"v"(wz[6]), [z7]"v"(wz[7]),
              [z8]"v"(wz[8]), [z9]"v"(wz[9]), [z10]"v"(wz[10]), [z11]"v"(wz[11]),
              [z12]"v"(wz[12]), [z13]"v"(wz[13]), [z14]"v"(wz[14]), [z15]"v"(wz[15]),
              [n0]"v"(wn[0]), [n1]"v"(wn[1]), [n2]"v"(wn[2]), [n3]"v"(wn[3]),
              [n4]"v"(wn[4]), [n5]"v"(wn[5]), [n6]"v"(wn[6]), [n7]"v"(wn[7]),
              [n8]"v"(wn[8]), [n9]"v"(wn[9]), [n10]"v"(wn[10]), [n11]"v"(wn[11]),
              [n12]"v"(wn[12]), [n13]"v"(wn[13]), [n14]"v"(wn[14]), [n15]"v"(wn[15])
            : "memory", "scc", "s20",
              "v33", "v36", "v37", "v38", "v39", "v40", "v41", "v42", "v43",
              "v44", "v45", "v46", "v47", "v48", "v49", "v50", "v51",
              "v52", "v53", "v54", "v55", "v56", "v57", "v58", "v59",
              "v60", "v61", "v62", "v63", "v64", "v65", "v66", "v67",
              "v68", "v69", "v70", "v71", "v72", "v74", "v75", "v76", "v77",
              "v78", "v80", "v81", "v82", "v83");

        // amortized y reductions (stride 33: conflict-free), one per stream
        float p0 = 0.0f, p1 = 0.0f, p2 = 0.0f, p3 = 0.0f;
        float q0 = 0.0f, q1 = 0.0f, q2 = 0.0f, q3 = 0.0f;
#pragma unroll
        for (int k = 0; k < 32; k += 4) {
            p0 += yrP[33 * j + k + 0];
            p1 += yrP[33 * j + k + 1];
            p2 += yrP[33 * j + k + 2];
            p3 += yrP[33 * j + k + 3];
            q0 += yrQ[33 * j + k + 0];
            q1 += yrQ[33 * j + k + 1];
            q2 += yrQ[33 * j + k + 2];
            q3 += yrQ[33 * j + k + 3];
        }
        ybP[t0 + j] = (p0 + p1) + (p2 + p3) + bo;
        ybQ[t0 + j] = (q0 + q1) + (q2 + q3) + bo;
        __builtin_amdgcn_wave_barrier();
    }

    out[(size_t)BB * TT + bP * H + j] = hP;
    out[(size_t)BB * TT + bQ * H + j] = hQ;
}

extern "C" void kernel_launch(void* const* d_in, const int* in_sizes, int n_in,
                              void* d_out, int out_size, void* d_ws, size_t ws_size,
                              hipStream_t stream) {
    const float* x     = (const float*)d_in[0];
    const float* h0    = (const float*)d_in[1];
    const float* W_ih  = (const float*)d_in[2];
    const float* W_hh  = (const float*)d_in[3];
    const float* b_ih  = (const float*)d_in[4];
    const float* b_hh  = (const float*)d_in[5];
    const float* W_out = (const float*)d_in[6];
    const float* b_out = (const float*)d_in[7];
    float* out = (float*)d_out;

    dim3 grid(256);    // 512 waves x 4 batches = 2048
    dim3 block(128);   // 2 waves
    gru_fused<<<grid, block, 0, stream>>>(x, h0, W_ih, W_hh, b_ih, b_hh,
                                          W_out, b_out, out);
}

// Round 12
// 285.874 us; speedup vs baseline: 1.6785x; 1.6785x over previous
//
#include <hip/hip_runtime.h>

// GRU: H=32, I=1, B=2048, T=1024, fused output Linear(32,1).
// v12 = v10 (half-wave per batch, full K per lane, 1024 waves = 1/SIMD,
// f16 weights + dot2) with stall surgery, keeping ALL SIMDs occupied
// (v11 showed dual-stream per-wave gains < the 2x idle-SIMD penalty):
//  * 2-step unroll; per-step DS group = [publish b16, 4x ds_read_b128,
//    y-write]; waits are lgkmcnt(1) (tolerate the trailing y-write) not (0)
//  * x prefetched one iteration ahead via ds_read_b64 (x is h-independent,
//    leaves the critical chain; v10 read it per-step inside the chain)
//  * y-stash stride 36 -> 33 (kills v10's 5.7M bank-conflict cycles)
//  * branch cost halved; bookkeeping in trans-hazard shadows; s_nop 3
//    after trans ops (v8/v10 absmax wobble = marginal hazard margin)

constexpr int H  = 32;
constexpr int TT = 1024;
constexpr int BB = 2048;

typedef _Float16 hf2 __attribute__((ext_vector_type(2)));

__device__ __forceinline__ unsigned pack2(float a, float b) {
    hf2 t; t.x = (_Float16)a; t.y = (_Float16)b;
    return __builtin_bit_cast(unsigned, t);
}

// 48 dot2 block: accumulates r,z,n for one step from h-regs v36-v51
#define DOT48                                          \
    "v_dot2_f32_f16 v68, %[r0], v36, %[br]\n\t"        \
    "v_dot2_f32_f16 v69, %[z0], v36, %[bz]\n\t"        \
    "v_dot2_f32_f16 v70, %[n0], v36, %[bn]\n\t"        \
    "v_dot2_f32_f16 v68, %[r1], v37, v68\n\t"          \
    "v_dot2_f32_f16 v69, %[z1], v37, v69\n\t"          \
    "v_dot2_f32_f16 v70, %[n1], v37, v70\n\t"          \
    "v_dot2_f32_f16 v68, %[r2], v38, v68\n\t"          \
    "v_dot2_f32_f16 v69, %[z2], v38, v69\n\t"          \
    "v_dot2_f32_f16 v70, %[n2], v38, v70\n\t"          \
    "v_dot2_f32_f16 v68, %[r3], v39, v68\n\t"          \
    "v_dot2_f32_f16 v69, %[z3], v39, v69\n\t"          \
    "v_dot2_f32_f16 v70, %[n3], v39, v70\n\t"          \
    "v_dot2_f32_f16 v68, %[r4], v40, v68\n\t"          \
    "v_dot2_f32_f16 v69, %[z4], v40, v69\n\t"          \
    "v_dot2_f32_f16 v70, %[n4], v40, v70\n\t"          \
    "v_dot2_f32_f16 v68, %[r5], v41, v68\n\t"          \
    "v_dot2_f32_f16 v69, %[z5], v41, v69\n\t"          \
    "v_dot2_f32_f16 v70, %[n5], v41, v70\n\t"          \
    "v_dot2_f32_f16 v68, %[r6], v42, v68\n\t"          \
    "v_dot2_f32_f16 v69, %[z6], v42, v69\n\t"          \
    "v_dot2_f32_f16 v70, %[n6], v42, v70\n\t"          \
    "v_dot2_f32_f16 v68, %[r7], v43, v68\n\t"          \
    "v_dot2_f32_f16 v69, %[z7], v43, v69\n\t"          \
    "v_dot2_f32_f16 v70, %[n7], v43, v70\n\t"          \
    "v_dot2_f32_f16 v68, %[r8], v44, v68\n\t"          \
    "v_dot2_f32_f16 v69, %[z8], v44, v69\n\t"          \
    "v_dot2_f32_f16 v70, %[n8], v44, v70\n\t"          \
    "v_dot2_f32_f16 v68, %[r9], v45, v68\n\t"          \
    "v_dot2_f32_f16 v69, %[z9], v45, v69\n\t"          \
    "v_dot2_f32_f16 v70, %[n9], v45, v70\n\t"          \
    "v_dot2_f32_f16 v68, %[r10], v46, v68\n\t"         \
    "v_dot2_f32_f16 v69, %[z10], v46, v69\n\t"         \
    "v_dot2_f32_f16 v70, %[n10], v46, v70\n\t"         \
    "v_dot2_f32_f16 v68, %[r11], v47, v68\n\t"         \
    "v_dot2_f32_f16 v69, %[z11], v47, v69\n\t"         \
    "v_dot2_f32_f16 v70, %[n11], v47, v70\n\t"         \
    "v_dot2_f32_f16 v68, %[r12], v48, v68\n\t"         \
    "v_dot2_f32_f16 v69, %[z12], v48, v69\n\t"         \
    "v_dot2_f32_f16 v70, %[n12], v48, v70\n\t"         \
    "v_dot2_f32_f16 v68, %[r13], v49, v68\n\t"         \
    "v_dot2_f32_f16 v69, %[z13], v49, v69\n\t"         \
    "v_dot2_f32_f16 v70, %[n13], v49, v70\n\t"         \
    "v_dot2_f32_f16 v68, %[r14], v50, v68\n\t"         \
    "v_dot2_f32_f16 v69, %[z14], v50, v69\n\t"         \
    "v_dot2_f32_f16 v70, %[n14], v50, v70\n\t"         \
    "v_dot2_f32_f16 v68, %[r15], v51, v68\n\t"         \
    "v_dot2_f32_f16 v69, %[z15], v51, v69\n\t"         \
    "v_dot2_f32_f16 v70, %[n15], v51, v70\n\t"

// gate tail: XREG = x register for this step, HREG = h register (updated)
#define TAIL(XREG, HREG)                               \
    "v_fmac_f32 v68, " XREG ", %[wir]\n\t"             \
    "v_fmac_f32 v69, " XREG ", %[wiz]\n\t"             \
    "v_exp_f32 v71, v68\n\t"                           \
    "v_exp_f32 v72, v69\n\t"                           \
    "v_fma_f32 v74, " XREG ", %[wi], %[bi]\n\t"        \
    "s_nop 3\n\t"                                      \
    "v_add_f32 v71, 1.0, v71\n\t"                      \
    "v_add_f32 v72, 1.0, v72\n\t"                      \
    "v_rcp_f32 v71, v71\n\t"                           \
    "v_rcp_f32 v72, v72\n\t"                           \
    "s_nop 3\n\t"                                      \
    "v_fmac_f32 v74, v71, v70\n\t"                     \
    "v_exp_f32 v75, v74\n\t"                           \
    "s_nop 3\n\t"                                      \
    "v_add_f32 v75, 1.0, v75\n\t"                      \
    "v_rcp_f32 v75, v75\n\t"                           \
    "s_nop 3\n\t"                                      \
    "v_fma_f32 v76, -2.0, v75, 1.0\n\t"                \
    "v_sub_f32 v77, " HREG ", v76\n\t"                 \
    "v_fma_f32 " HREG ", v72, v77, v76\n\t"

__global__ __launch_bounds__(256, 1)
void gru_fused(const float* __restrict__ x,      // [B,T]
               const float* __restrict__ h0,     // [1,B,H]
               const float* __restrict__ W_ih,   // [3H,1]
               const float* __restrict__ W_hh,   // [3H,H]
               const float* __restrict__ b_ih,   // [3H]
               const float* __restrict__ b_hh,   // [3H]
               const float* __restrict__ W_out,  // [1,H]
               const float* __restrict__ b_out,  // [1]
               float* __restrict__ out)          // y[B,T] ++ h_n[B,H]
{
    __shared__ __align__(16) _Float16 hbuf[4][64];   // [wave][half*32+unit]
    __shared__ __align__(8) float xstage[4][2][36];  // [wave][half][step] (+pad)
    __shared__ float ybuf[4][2][33 * 32];            // [wave][half][33*s + j]

    const int tid  = threadIdx.x;
    const int w    = tid >> 6;
    const int lane = tid & 63;
    const int half = lane >> 5;
    const int j    = lane & 31;
    const int gw   = (blockIdx.x << 2) | w;   // 0..1023
    const int b    = (gw << 1) | half;        // this lane's batch

    const float NL2E = -1.44269504f;
    const float P2L2 =  2.88539008f;

    const float* Wrp = &W_hh[(0 * H + j) * H];
    const float* Wzp = &W_hh[(1 * H + j) * H];
    const float* Wnp = &W_hh[(2 * H + j) * H];
    unsigned wr[16], wz[16], wn[16];
#pragma unroll
    for (int k = 0; k < 16; ++k) {
        wr[k] = pack2(Wrp[2 * k] * NL2E, Wrp[2 * k + 1] * NL2E);
        wz[k] = pack2(Wzp[2 * k] * NL2E, Wzp[2 * k + 1] * NL2E);
        wn[k] = pack2(Wnp[2 * k] * P2L2, Wnp[2 * k + 1] * P2L2);
    }
    const float wir = W_ih[j] * NL2E;
    const float wiz = W_ih[H + j] * NL2E;
    const float br  = (b_ih[j] + b_hh[j]) * NL2E;
    const float bz  = (b_ih[H + j] + b_hh[H + j]) * NL2E;
    const float bhn = b_hh[2 * H + j] * P2L2;
    const float win = W_ih[2 * H + j] * P2L2;
    const float bin = b_ih[2 * H + j] * P2L2;
    const float wo  = W_out[j];
    const float bo  = b_out[0];

    float h = h0[b * H + j];

    const float* xb = x + (size_t)b * TT;
    float*       yb = out + (size_t)b * TT;

    const unsigned ha = (unsigned)(size_t)&hbuf[w][half * 32 + j];   // publish
    const unsigned hr = (unsigned)(size_t)&hbuf[w][half * 32];       // 64B reads
    const unsigned xw = (unsigned)(size_t)&xstage[w][half][j];       // stage
    const unsigned xa = (unsigned)(size_t)&xstage[w][half][0];       // b64 reads
    const unsigned ya = (unsigned)(size_t)&ybuf[w][half][j];         // y stash
    const float* yr = &ybuf[w][half][0];

#pragma unroll 1
    for (int t0 = 0; t0 < TT; t0 += 32) {
        const float xv = xb[t0 + j];

        asm volatile(
            "s_mov_b32 s20, 16\n\t"
            "v_mov_b32 v82, %[ya]\n\t"
            "v_mov_b32 v83, %[xa]\n\t"
            // prologue: queue = [stage, xAB, pubA, rA x4, ywrDummy] (8)
            "ds_write_b32 %[xw], %[xv]\n\t"
            "ds_read_b64 v[80:81], v83\n\t"            // x_0, x_1
            "v_cvt_f16_f32 v33, %[h]\n\t"
            "ds_write_b16 %[ha], v33\n\t"
            "ds_read_b128 v[36:39], %[hr]\n\t"
            "ds_read_b128 v[40:43], %[hr] offset:16\n\t"
            "ds_read_b128 v[44:47], %[hr] offset:32\n\t"
            "ds_read_b128 v[48:51], %[hr] offset:48\n\t"
            "ds_write_b32 v82, v78\n\t"                // dummy y (overwritten)

            "L_gru_%=:\n\t"
            // ---------- step A (even) ----------
            "s_waitcnt lgkmcnt(1)\n\t"                 // h-reads + x landed
            DOT48
            TAIL("v80", "%[h]")
            // publish + reads for step B, then y-write A (after reads)
            "v_cvt_f16_f32 v33, %[h]\n\t"
            "ds_write_b16 %[ha], v33\n\t"
            "ds_read_b128 v[36:39], %[hr]\n\t"
            "ds_read_b128 v[40:43], %[hr] offset:16\n\t"
            "ds_read_b128 v[44:47], %[hr] offset:32\n\t"
            "ds_read_b128 v[48:51], %[hr] offset:48\n\t"
            "v_mul_f32 v78, %[wo], %[h]\n\t"
            "ds_write_b32 v82, v78\n\t"                // ywrA
            // ---------- step B (odd) ----------
            "s_waitcnt lgkmcnt(1)\n\t"                 // B's reads landed (ywrA may linger)
            DOT48
            TAIL("v81", "%[h]")
            // publish + reads for next iter's step A; prefetch next x pair
            "v_cvt_f16_f32 v33, %[h]\n\t"
            "ds_write_b16 %[ha], v33\n\t"
            "ds_read_b128 v[36:39], %[hr]\n\t"
            "ds_read_b128 v[40:43], %[hr] offset:16\n\t"
            "ds_read_b128 v[44:47], %[hr] offset:32\n\t"
            "ds_read_b128 v[48:51], %[hr] offset:48\n\t"
            "ds_read_b64 v[80:81], v83 offset:8\n\t"   // x_{s+2}, x_{s+3}
            "v_mul_f32 v78, %[wo], %[h]\n\t"
            "ds_write_b32 v82, v78 offset:132\n\t"     // ywrB
            // bookkeeping
            "v_add_u32 v82, 264, v82\n\t"
            "v_add_u32 v83, 8, v83\n\t"
            "s_sub_i32 s20, s20, 1\n\t"
            "s_cmp_gt_i32 s20, 0\n\t"
            "s_cbranch_scc1 L_gru_%=\n\t"
            "s_waitcnt lgkmcnt(0)"
            : [h]"+v"(h)
            : [xv]"v"(xv), [ha]"v"(ha), [hr]"v"(hr), [xw]"v"(xw), [xa]"v"(xa),
              [ya]"v"(ya),
              [wir]"v"(wir), [wiz]"v"(wiz), [wi]"v"(win), [bi]"v"(bin),
              [wo]"v"(wo), [br]"v"(br), [bz]"v"(bz), [bn]"v"(bhn),
              [r0]"v"(wr[0]), [r1]"v"(wr[1]), [r2]"v"(wr[2]), [r3]"v"(wr[3]),
              [r4]"v"(wr[4]), [r5]"v"(wr[5]), [r6]"v"(wr[6]), [r7]"v"(wr[7]),
              [r8]"v"(wr[8]), [r9]"v"(wr[9]), [r10]"v"(wr[10]), [r11]"v"(wr[11]),
              [r12]"v"(wr[12]), [r13]"v"(wr[13]), [r14]"v"(wr[14]), [r15]"v"(wr[15]),
              [z0]"v"(wz[0]), [z1]"v"(wz[1]), [z2]"v"(wz[2]), [z3]"v"(wz[3]),
              [z4]"v"(wz[4]), [z5]"v"(wz[5]), [z6]"v"(wz[6]), [z7]"v"(wz[7]),
              [z8]"v"(wz[8]), [z9]"v"(wz[9]), [z10]"v"(wz[10]), [z11]"v"(wz[11]),
              [z12]"v"(wz[12]), [z13]"v"(wz[13]), [z14]"v"(wz[14]), [z15]"v"(wz[15]),
              [n0]"v"(wn[0]), [n1]"v"(wn[1]), [n2]"v"(wn[2]), [n3]"v"(wn[3]),
              [n4]"v"(wn[4]), [n5]"v"(wn[5]), [n6]"v"(wn[6]), [n7]"v"(wn[7]),
              [n8]"v"(wn[8]), [n9]"v"(wn[9]), [n10]"v"(wn[10]), [n11]"v"(wn[11]),
              [n12]"v"(wn[12]), [n13]"v"(wn[13]), [n14]"v"(wn[14]), [n15]"v"(wn[15])
            : "memory", "scc", "s20",
              "v33", "v36", "v37", "v38", "v39", "v40", "v41", "v42", "v43",
              "v44", "v45", "v46", "v47", "v48", "v49", "v50", "v51",
              "v68", "v69", "v70", "v71", "v72", "v74", "v75", "v76", "v77",
              "v78", "v80", "v81", "v82", "v83");

        // amortized y reduction: stride 33 (conflict-free across j)
        float s0 = 0.0f, s1 = 0.0f, s2 = 0.0f, s3 = 0.0f;
#pragma unroll
        for (int k = 0; k < 32; k += 4) {
            s0 += yr[33 * j + k + 0];
            s1 += yr[33 * j + k + 1];
            s2 += yr[33 * j + k + 2];
            s3 += yr[33 * j + k + 3];
        }
        yb[t0 + j] = (s0 + s1) + (s2 + s3) + bo;
        __builtin_amdgcn_wave_barrier();
    }

    out[(size_t)BB * TT + b * H + j] = h;

#undef DOT48
#undef TAIL
}

extern "C" void kernel_launch(void* const* d_in, const int* in_sizes, int n_in,
                              void* d_out, int out_size, void* d_ws, size_t ws_size,
                              hipStream_t stream) {
    const float* x     = (const float*)d_in[0];
    const float* h0    = (const float*)d_in[1];
    const float* W_ih  = (const float*)d_in[2];
    const float* W_hh  = (const float*)d_in[3];
    const float* b_ih  = (const float*)d_in[4];
    const float* b_hh  = (const float*)d_in[5];
    const float* W_out = (const float*)d_in[6];
    const float* b_out = (const float*)d_in[7];
    float* out = (float*)d_out;

    dim3 grid(BB / 8);   // 256 blocks: 4 waves x 2 batches each = 1024 waves
    dim3 block(256);
    gru_fused<<<grid, block, 0, stream>>>(x, h0, W_ih, W_hh, b_ih, b_hh,
                                          W_out, b_out, out);
}